// Round 13
// baseline (301.460 us; speedup 1.0000x reference)
//
#include <hip/hip_runtime.h>
#include <hip/hip_bf16.h>
#include <stdint.h>

#define BATCH 512
#define NN 32
#define T_IN 12
#define HID 64
#define HEADS 8
#define OUT_CH 9
#define EPB (NN*8)       // 256 edges per batch (before self loops)
#define ETOT (EPB+NN)    // 288 with self loops
#define F1 (HEADS*HID)   // 512

using u16 = unsigned short;
using u32 = unsigned int;
typedef _Float16 f16;
typedef _Float16 f16x2 __attribute__((ext_vector_type(2)));
typedef u32 v4u __attribute__((ext_vector_type(4)));
typedef float v4f __attribute__((ext_vector_type(4)));

__device__ __forceinline__ float bf2f(u16 u){ return __uint_as_float(((u32)u)<<16); }
__device__ __forceinline__ u16 f2bf(float f){
    u32 x = __float_as_uint(f);
    u32 r = (x + 0x7FFFu + ((x>>16)&1u))>>16;
    return (u16)r;
}
__device__ __forceinline__ u32 packf16(float a, float b){
    f16x2 p; p.x=(f16)a; p.y=(f16)b; return __builtin_bit_cast(u32,p);
}
__device__ __forceinline__ u16 f2h16(float a){ f16 h=(f16)a; return __builtin_bit_cast(u16,h); }
__device__ __forceinline__ float h16f(u16 v){ f16 h=__builtin_bit_cast(f16,v); return (float)h; }
__device__ __forceinline__ float lof(u32 w){ return (float)__builtin_bit_cast(f16x2,w).x; }
__device__ __forceinline__ float hif(u32 w){ return (float)__builtin_bit_cast(f16x2,w).y; }
__device__ __forceinline__ float dot2(u32 a, u32 b, float c){
#if __has_builtin(__builtin_amdgcn_fdot2)
    return __builtin_amdgcn_fdot2(__builtin_bit_cast(f16x2,a), __builtin_bit_cast(f16x2,b), c, false);
#else
    return fmaf(lof(a),lof(b), fmaf(hif(a),hif(b), c));
#endif
}
__device__ __forceinline__ float elu1(float x){ return x > 0.f ? x : (__expf(x)-1.f); }
__device__ __forceinline__ float sigm(float x){ return 1.f/(1.f+__expf(-x)); }
__device__ __forceinline__ float tanh_(float x){ return 1.f - 2.f/(__expf(2.f*x)+1.f); }
__device__ __forceinline__ u32 fenc(float v){
    u32 b=__float_as_uint(v);
    return (b&0x80000000u) ? ~b : (b|0x80000000u);
}
__device__ __forceinline__ float fdec(u32 k){
    return __uint_as_float((k&0x80000000u) ? (k&0x7FFFFFFFu) : ~k);
}

#define DOT4(acc,A,W) do{ acc=dot2(A.x,W.x,acc); acc=dot2(A.y,W.y,acc); \
                          acc=dot2(A.z,W.z,acc); acc=dot2(A.w,W.w,acc); }while(0)
#define DOT32(acc,A0,A1,A2,A3,A4,A5,A6,A7,W0,W1,W2,W3,W4,W5,W6,W7) do{ \
    DOT4(acc,A0,W0); DOT4(acc,A1,W1); DOT4(acc,A2,W2); DOT4(acc,A3,W3); \
    DOT4(acc,A4,W4); DOT4(acc,A5,W5); DOT4(acc,A6,W6); DOT4(acc,A7,W7); }while(0)

// ------------------------------------------------ dtype detection (fp32 vs bf16)
__global__ __launch_bounds__(256) void k_detect(const u32* __restrict__ xw, int* __restrict__ flag){
    __shared__ int cnt;
    if(threadIdx.x==0) cnt=0;
    __syncthreads();
    int c=0;
    for(int i=threadIdx.x;i<4096;i+=256){
        u32 w=xw[i];
        if(w & 0x7FFFFFFFu){
            u32 el=(w>>7)&0xFFu;
            if(el>=0x90u) c++;
        }
    }
    atomicAdd(&cnt,c);
    __syncthreads();
    if(threadIdx.x==0) *flag = (cnt>256) ? 1 : 0;   // 1 = fp32 inputs, 0 = bf16
}

// ------------------------------------------------ canonicalize inputs into ws (fp32)
struct CvtDesc {
    const void* src[16];
    void*       dst[16];
    int         n[16];
};

__global__ __launch_bounds__(256) void k_convert(CvtDesc d, const int* __restrict__ flag){
    const int seg = blockIdx.x;
    const int f = *flag;
    const void* s = d.src[seg];
    const int n = d.n[seg];
    const int stride = gridDim.y*256;
    float* o=(float*)d.dst[seg];
    for(int i=blockIdx.y*256+threadIdx.x;i<n;i+=stride)
        o[i] = f ? ((const float*)s)[i] : bf2f(((const u16*)s)[i]);
}

// W2 interleave + GRU weight packing in one launch (blocks 0-127: W2i; 128-223: wpk)
__global__ __launch_bounds__(256) void k_prep(
    const void* __restrict__ W2src, u16* __restrict__ W2i,
    const void* __restrict__ Wi1, const void* __restrict__ Wh1,
    const void* __restrict__ Wi2, const void* __restrict__ Wh2,
    u32* __restrict__ wpk, const int* __restrict__ flag)
{
    const int f=*flag;
    if(blockIdx.x<128){
        int i = blockIdx.x*256+threadIdx.x;        // i = k*64+j
        int k=i>>6, j=i&63;
        float v = f? ((const float*)W2src)[i] : bf2f(((const u16*)W2src)[i]);
        W2i[ (((size_t)(k>>3)*64 + j)<<3) + (k&7) ] = f2h16(v);
    } else {
        int w = (blockIdx.x-128)*256+threadIdx.x;  // 0..24575
        int m = w/6144;
        int rem = w - m*6144;
        int row = rem>>5, kw = rem&31;
        const void* s = (m==0)?Wi1 : (m==1)?Wh1 : (m==2)?Wi2 : Wh2;
        int K = (m==0)?32:64;
        int k0=2*kw, k1=k0+1;
        float v0=0.f, v1=0.f;
        if(k0<K) v0 = f? ((const float*)s)[row*K+k0] : bf2f(((const u16*)s)[row*K+k0]);
        if(k1<K) v1 = f? ((const float*)s)[row*K+k1] : bf2f(((const u16*)s)[row*K+k1]);
        wpk[w]=packf16(v0,v1);
    }
}

// ---------------------------------------------------------------- GAT layer 1
__global__ __launch_bounds__(256,2) void k_gat1(
    const float* __restrict__ x, const int* __restrict__ ei,
    const float* __restrict__ W1, const float* __restrict__ a_s, const float* __restrict__ a_d,
    const float* __restrict__ b1, u32* __restrict__ h1g)
{
    const int b = blockIdx.x, t = threadIdx.x;
    __shared__ __align__(16) float s_x[NN][12];
    __shared__ float s_W1[T_IN*F1];
    __shared__ __align__(16) u16 s_h[NN][520];
    __shared__ __align__(16) u32 s_aspk[HEADS*32], s_adpk[HEADS*32];
    __shared__ float s_es[NN][HEADS], s_ed[NN][HEADS];
    __shared__ unsigned char s_src[ETOT], s_dst[ETOT];
    __shared__ float s_al[HEADS][ETOT];
    __shared__ u32 s_mx[NN*HEADS];
    __shared__ float s_sm[NN*HEADS], s_inv[NN*HEADS];
    __shared__ int s_cnt[NN], s_off[NN], s_fil[NN];
    __shared__ short s_lst[ETOT];

    for(int i=t;i<NN*T_IN;i+=256) s_x[i/12][i%12] = x[b*NN*T_IN + i];
    for(int i=t;i<T_IN*F1;i+=256) s_W1[i]=W1[i];
    s_aspk[t]=packf16(a_s[2*t],a_s[2*t+1]);
    s_adpk[t]=packf16(a_d[2*t],a_d[2*t+1]);
    s_mx[t]=0u; s_sm[t]=0.f;
    if(t<EPB){
        s_src[t] = (unsigned char)(ei[b*EPB+t] - b*NN);
        s_dst[t] = (unsigned char)(ei[(size_t)BATCH*EPB + b*EPB+t] - b*NN);
    }
    if(t<NN){ s_src[EPB+t]=s_dst[EPB+t]=(unsigned char)t; s_cnt[t]=0; s_fil[t]=0; }
    __syncthreads();

    {
        v4f Wa0,Wa1,Wa2,Wb0,Wb1,Wb2;
        Wa0.x=s_W1[0*F1+t]; Wa0.y=s_W1[1*F1+t]; Wa0.z=s_W1[2*F1+t]; Wa0.w=s_W1[3*F1+t];
        Wa1.x=s_W1[4*F1+t]; Wa1.y=s_W1[5*F1+t]; Wa1.z=s_W1[6*F1+t]; Wa1.w=s_W1[7*F1+t];
        Wa2.x=s_W1[8*F1+t]; Wa2.y=s_W1[9*F1+t]; Wa2.z=s_W1[10*F1+t]; Wa2.w=s_W1[11*F1+t];
        Wb0.x=s_W1[0*F1+t+256]; Wb0.y=s_W1[1*F1+t+256]; Wb0.z=s_W1[2*F1+t+256]; Wb0.w=s_W1[3*F1+t+256];
        Wb1.x=s_W1[4*F1+t+256]; Wb1.y=s_W1[5*F1+t+256]; Wb1.z=s_W1[6*F1+t+256]; Wb1.w=s_W1[7*F1+t+256];
        Wb2.x=s_W1[8*F1+t+256]; Wb2.y=s_W1[9*F1+t+256]; Wb2.z=s_W1[10*F1+t+256]; Wb2.w=s_W1[11*F1+t+256];
        for(int n=0;n<NN;n++){
            const float4* xp=(const float4*)s_x[n];
            float4 xa=xp[0], xb=xp[1], xc=xp[2];
            float A=0.f,B=0.f;
            A=fmaf(xa.x,Wa0.x,A); A=fmaf(xa.y,Wa0.y,A); A=fmaf(xa.z,Wa0.z,A); A=fmaf(xa.w,Wa0.w,A);
            A=fmaf(xb.x,Wa1.x,A); A=fmaf(xb.y,Wa1.y,A); A=fmaf(xb.z,Wa1.z,A); A=fmaf(xb.w,Wa1.w,A);
            A=fmaf(xc.x,Wa2.x,A); A=fmaf(xc.y,Wa2.y,A); A=fmaf(xc.z,Wa2.z,A); A=fmaf(xc.w,Wa2.w,A);
            B=fmaf(xa.x,Wb0.x,B); B=fmaf(xa.y,Wb0.y,B); B=fmaf(xa.z,Wb0.z,B); B=fmaf(xa.w,Wb0.w,B);
            B=fmaf(xb.x,Wb1.x,B); B=fmaf(xb.y,Wb1.y,B); B=fmaf(xb.z,Wb1.z,B); B=fmaf(xb.w,Wb1.w,B);
            B=fmaf(xc.x,Wb2.x,B); B=fmaf(xc.y,Wb2.y,B); B=fmaf(xc.z,Wb2.z,B); B=fmaf(xc.w,Wb2.w,B);
            s_h[n][t]=f2h16(A); s_h[n][t+256]=f2h16(B);
        }
    }
    for(int e=t;e<ETOT;e+=256) atomicAdd(&s_cnt[s_dst[e]],1);
    __syncthreads();

    {
        int n=t&31, hd=t>>5;
        const v4u* hp=(const v4u*)((const u16*)s_h[n] + hd*64);
        v4u h0=hp[0],h1=hp[1],h2=hp[2],h3=hp[3],h4=hp[4],h5=hp[5],h6=hp[6],h7=hp[7];
        const v4u* ap=(const v4u*)&s_aspk[hd*32];
        const v4u* dp=(const v4u*)&s_adpk[hd*32];
        float e1=0.f,e2=0.f;
        { v4u w=ap[0]; DOT4(e1,h0,w); w=ap[1]; DOT4(e1,h1,w); w=ap[2]; DOT4(e1,h2,w); w=ap[3]; DOT4(e1,h3,w);
          w=ap[4]; DOT4(e1,h4,w); w=ap[5]; DOT4(e1,h5,w); w=ap[6]; DOT4(e1,h6,w); w=ap[7]; DOT4(e1,h7,w); }
        { v4u w=dp[0]; DOT4(e2,h0,w); w=dp[1]; DOT4(e2,h1,w); w=dp[2]; DOT4(e2,h2,w); w=dp[3]; DOT4(e2,h3,w);
          w=dp[4]; DOT4(e2,h4,w); w=dp[5]; DOT4(e2,h5,w); w=dp[6]; DOT4(e2,h6,w); w=dp[7]; DOT4(e2,h7,w); }
        s_es[n][hd]=e1; s_ed[n][hd]=e2;
    }
    if(t==0){ int o=0; for(int i=0;i<NN;i++){ s_off[i]=o; o+=s_cnt[i]; } }
    __syncthreads();

    for(int e=t;e<ETOT;e+=256){
        int d=s_dst[e]; int p=atomicAdd(&s_fil[d],1); s_lst[s_off[d]+p]=(short)e;
    }
    for(int i=t;i<ETOT*HEADS;i+=256){
        int hd=i/ETOT, e=i-hd*ETOT;
        int sr=s_src[e], d=s_dst[e];
        float v = s_es[sr][hd]+s_ed[d][hd];
        v = v>0.f? v : 0.2f*v;
        s_al[hd][e]=v;
        atomicMax(&s_mx[d*8+hd], fenc(v));
    }
    __syncthreads();

    for(int i=t;i<ETOT*HEADS;i+=256){
        int hd=i/ETOT, e=i-hd*ETOT;
        int d=s_dst[e];
        float p=__expf(s_al[hd][e]-fdec(s_mx[d*8+hd]));
        s_al[hd][e]=p;
        atomicAdd(&s_sm[d*8+hd], p);
    }
    __syncthreads();
    s_inv[t]=1.f/(s_sm[t]+1e-16f);
    __syncthreads();

    {
        int d=t&31, hd=t>>5;
        int o=s_off[d], cnt=s_cnt[d];
        float inv=s_inv[d*8+hd];
        size_t obase = ((size_t)(b*NN+d))*256 + hd*32;
        #pragma unroll
        for(int ch=0;ch<2;ch++){
            v4f a0=0,a1=0,a2=0,a3=0,a4=0,a5=0,a6=0,a7=0;
            for(int i=0;i<cnt;i++){
                int e=s_lst[o+i]; float av=s_al[hd][e]; int sr=s_src[e];
                const v4u* hp=(const v4u*)((const u16*)s_h[sr] + hd*64 + ch*32);
                v4u p0=hp[0],p1=hp[1],p2=hp[2],p3=hp[3];
                a0.x=fmaf(av,lof(p0.x),a0.x); a0.y=fmaf(av,hif(p0.x),a0.y);
                a0.z=fmaf(av,lof(p0.y),a0.z); a0.w=fmaf(av,hif(p0.y),a0.w);
                a1.x=fmaf(av,lof(p0.z),a1.x); a1.y=fmaf(av,hif(p0.z),a1.y);
                a1.z=fmaf(av,lof(p0.w),a1.z); a1.w=fmaf(av,hif(p0.w),a1.w);
                a2.x=fmaf(av,lof(p1.x),a2.x); a2.y=fmaf(av,hif(p1.x),a2.y);
                a2.z=fmaf(av,lof(p1.y),a2.z); a2.w=fmaf(av,hif(p1.y),a2.w);
                a3.x=fmaf(av,lof(p1.z),a3.x); a3.y=fmaf(av,hif(p1.z),a3.y);
                a3.z=fmaf(av,lof(p1.w),a3.z); a3.w=fmaf(av,hif(p1.w),a3.w);
                a4.x=fmaf(av,lof(p2.x),a4.x); a4.y=fmaf(av,hif(p2.x),a4.y);
                a4.z=fmaf(av,lof(p2.y),a4.z); a4.w=fmaf(av,hif(p2.y),a4.w);
                a5.x=fmaf(av,lof(p2.z),a5.x); a5.y=fmaf(av,hif(p2.z),a5.y);
                a5.z=fmaf(av,lof(p2.w),a5.z); a5.w=fmaf(av,hif(p2.w),a5.w);
                a6.x=fmaf(av,lof(p3.x),a6.x); a6.y=fmaf(av,hif(p3.x),a6.y);
                a6.z=fmaf(av,lof(p3.y),a6.z); a6.w=fmaf(av,hif(p3.y),a6.w);
                a7.x=fmaf(av,lof(p3.z),a7.x); a7.y=fmaf(av,hif(p3.z),a7.y);
                a7.z=fmaf(av,lof(p3.w),a7.z); a7.w=fmaf(av,hif(p3.w),a7.w);
            }
            const float* bp = b1 + hd*64 + ch*32;
            u32* op = h1g + obase + ch*16;
            op[0] = packf16(elu1(a0.x*inv+bp[0]),  elu1(a0.y*inv+bp[1]));
            op[1] = packf16(elu1(a0.z*inv+bp[2]),  elu1(a0.w*inv+bp[3]));
            op[2] = packf16(elu1(a1.x*inv+bp[4]),  elu1(a1.y*inv+bp[5]));
            op[3] = packf16(elu1(a1.z*inv+bp[6]),  elu1(a1.w*inv+bp[7]));
            op[4] = packf16(elu1(a2.x*inv+bp[8]),  elu1(a2.y*inv+bp[9]));
            op[5] = packf16(elu1(a2.z*inv+bp[10]), elu1(a2.w*inv+bp[11]));
            op[6] = packf16(elu1(a3.x*inv+bp[12]), elu1(a3.y*inv+bp[13]));
            op[7] = packf16(elu1(a3.z*inv+bp[14]), elu1(a3.w*inv+bp[15]));
            op[8] = packf16(elu1(a4.x*inv+bp[16]), elu1(a4.y*inv+bp[17]));
            op[9] = packf16(elu1(a4.z*inv+bp[18]), elu1(a4.w*inv+bp[19]));
            op[10]= packf16(elu1(a5.x*inv+bp[20]), elu1(a5.y*inv+bp[21]));
            op[11]= packf16(elu1(a5.z*inv+bp[22]), elu1(a5.w*inv+bp[23]));
            op[12]= packf16(elu1(a6.x*inv+bp[24]), elu1(a6.y*inv+bp[25]));
            op[13]= packf16(elu1(a6.z*inv+bp[26]), elu1(a6.w*inv+bp[27]));
            op[14]= packf16(elu1(a7.x*inv+bp[28]), elu1(a7.y*inv+bp[29]));
            op[15]= packf16(elu1(a7.z*inv+bp[30]), elu1(a7.w*inv+bp[31]));
        }
    }
}

// --------------------------------------------- GAT layer 2 + LayerNorm (+transpose)
__global__ __launch_bounds__(256,2) void k_gat2ln(
    const u32* __restrict__ h1g, const int* __restrict__ ei,
    const uint4* __restrict__ W2i, const float* __restrict__ a_s2, const float* __restrict__ a_d2,
    const float* __restrict__ b2, const float* __restrict__ gam, const float* __restrict__ bet,
    float* __restrict__ hlng)
{
    const int b=blockIdx.x, t=threadIdx.x;
    __shared__ __align__(16) u32 s_h1[NN*260];
    __shared__ float s_h2[NN][HID];
    __shared__ float s_es[NN], s_ed[NN];
    __shared__ unsigned char s_src[ETOT], s_dst[ETOT];
    __shared__ float s_al[ETOT];
    __shared__ u32 s_mx[NN];
    __shared__ float s_sm[NN], s_inv[NN];
    __shared__ int s_cnt[NN], s_off[NN], s_fil[NN];
    __shared__ short s_lst[ETOT];

    { const u32* g = h1g + (size_t)b*8192;
      for(int w=t; w<8192; w+=256){ int n=w>>8, c=w&255; s_h1[n*260+c]=g[w]; } }
    if(t<EPB){
        s_src[t]=(unsigned char)(ei[b*EPB+t]-b*NN);
        s_dst[t]=(unsigned char)(ei[(size_t)BATCH*EPB+b*EPB+t]-b*NN);
    }
    if(t<NN){ s_src[EPB+t]=s_dst[EPB+t]=(unsigned char)t;
              s_cnt[t]=0; s_fil[t]=0; s_mx[t]=0u; s_sm[t]=0.f; }
    __syncthreads();

    for(int e=t;e<ETOT;e+=256) atomicAdd(&s_cnt[s_dst[e]],1);
    {
        int n0=(t>>5)<<2, j0=(t&31)<<1;
        const u32* r0=&s_h1[(n0+0)*260];
        const u32* r1=&s_h1[(n0+1)*260];
        const u32* r2=&s_h1[(n0+2)*260];
        const u32* r3=&s_h1[(n0+3)*260];
        float a00=0,a01=0,a10=0,a11=0,a20=0,a21=0,a30=0,a31=0;
        for(int kb=0;kb<64;kb++){
            uint4 A0=*(const uint4*)&r0[kb*4];
            uint4 A1=*(const uint4*)&r1[kb*4];
            uint4 A2=*(const uint4*)&r2[kb*4];
            uint4 A3=*(const uint4*)&r3[kb*4];
            const uint4* wp=&W2i[kb*64+j0];
            uint4 w0=wp[0], w1=wp[1];
            a00=dot2(A0.x,w0.x,a00); a00=dot2(A0.y,w0.y,a00); a00=dot2(A0.z,w0.z,a00); a00=dot2(A0.w,w0.w,a00);
            a01=dot2(A0.x,w1.x,a01); a01=dot2(A0.y,w1.y,a01); a01=dot2(A0.z,w1.z,a01); a01=dot2(A0.w,w1.w,a01);
            a10=dot2(A1.x,w0.x,a10); a10=dot2(A1.y,w0.y,a10); a10=dot2(A1.z,w0.z,a10); a10=dot2(A1.w,w0.w,a10);
            a11=dot2(A1.x,w1.x,a11); a11=dot2(A1.y,w1.y,a11); a11=dot2(A1.z,w1.z,a11); a11=dot2(A1.w,w1.w,a11);
            a20=dot2(A2.x,w0.x,a20); a20=dot2(A2.y,w0.y,a20); a20=dot2(A2.z,w0.z,a20); a20=dot2(A2.w,w0.w,a20);
            a21=dot2(A2.x,w1.x,a21); a21=dot2(A2.y,w1.y,a21); a21=dot2(A2.z,w1.z,a21); a21=dot2(A2.w,w1.w,a21);
            a30=dot2(A3.x,w0.x,a30); a30=dot2(A3.y,w0.y,a30); a30=dot2(A3.z,w0.z,a30); a30=dot2(A3.w,w0.w,a30);
            a31=dot2(A3.x,w1.x,a31); a31=dot2(A3.y,w1.y,a31); a31=dot2(A3.z,w1.z,a31); a31=dot2(A3.w,w1.w,a31);
        }
        s_h2[n0+0][j0]=a00; s_h2[n0+0][j0+1]=a01;
        s_h2[n0+1][j0]=a10; s_h2[n0+1][j0+1]=a11;
        s_h2[n0+2][j0]=a20; s_h2[n0+2][j0+1]=a21;
        s_h2[n0+3][j0]=a30; s_h2[n0+3][j0+1]=a31;
    }
    __syncthreads();

    {
        int n=t>>3, g=t&7;
        float e1=0,e2=0;
        #pragma unroll
        for(int cc=0; cc<8; cc++){
            float hv = s_h2[n][g*8+cc];
            e1 += hv*a_s2[g*8+cc];
            e2 += hv*a_d2[g*8+cc];
        }
        #pragma unroll
        for(int m=1;m<8;m<<=1){ e1 += __shfl_xor(e1,m,64); e2 += __shfl_xor(e2,m,64); }
        if(g==0){ s_es[n]=e1; s_ed[n]=e2; }
    }
    if(t==0){ int o=0; for(int i=0;i<NN;i++){ s_off[i]=o; o+=s_cnt[i]; } }
    __syncthreads();

    for(int e=t;e<ETOT;e+=256){
        int d=s_dst[e]; int p=atomicAdd(&s_fil[d],1); s_lst[s_off[d]+p]=(short)e;
    }
    for(int e=t;e<ETOT;e+=256){
        int d=s_dst[e];
        float v = s_es[s_src[e]] + s_ed[d];
        v = v>0.f? v:0.2f*v;
        s_al[e]=v;
        atomicMax(&s_mx[d], fenc(v));
    }
    __syncthreads();

    for(int e=t;e<ETOT;e+=256){
        int d=s_dst[e];
        float p=__expf(s_al[e]-fdec(s_mx[d]));
        s_al[e]=p;
        atomicAdd(&s_sm[d], p);
    }
    __syncthreads();
    if(t<NN) s_inv[t]=1.f/(s_sm[t]+1e-16f);
    __syncthreads();

    {
        int n=t>>3, g=t&7;
        v4f a0=0, a1=0;
        int o=s_off[n], cnt=s_cnt[n];
        float inv=s_inv[n];
        for(int i=0;i<cnt;i++){
            int e=s_lst[o+i]; float a=s_al[e]; int sr=s_src[e];
            const float4* hp=(const float4*)&s_h2[sr][g*8];
            float4 v0=hp[0], v1=hp[1];
            a0.x=fmaf(a,v0.x,a0.x); a0.y=fmaf(a,v0.y,a0.y); a0.z=fmaf(a,v0.z,a0.z); a0.w=fmaf(a,v0.w,a0.w);
            a1.x=fmaf(a,v1.x,a1.x); a1.y=fmaf(a,v1.y,a1.y); a1.z=fmaf(a,v1.z,a1.z); a1.w=fmaf(a,v1.w,a1.w);
        }
        const float* bp=b2+g*8;
        float v0=elu1(a0.x*inv+bp[0]), v1=elu1(a0.y*inv+bp[1]);
        float v2=elu1(a0.z*inv+bp[2]), v3=elu1(a0.w*inv+bp[3]);
        float v4=elu1(a1.x*inv+bp[4]), v5=elu1(a1.y*inv+bp[5]);
        float v6=elu1(a1.z*inv+bp[6]), v7=elu1(a1.w*inv+bp[7]);
        float sum=v0+v1+v2+v3+v4+v5+v6+v7;
        float sq=v0*v0+v1*v1+v2*v2+v3*v3+v4*v4+v5*v5+v6*v6+v7*v7;
        #pragma unroll
        for(int m=1;m<8;m<<=1){ sum+=__shfl_xor(sum,m,64); sq+=__shfl_xor(sq,m,64); }
        float mu = sum*(1.f/64.f);
        float var = sq*(1.f/64.f) - mu*mu;
        float rs = rsqrtf(var + 1e-5f);
        float* outp = hlng + (size_t)b*HID*NN;
        int c=g*8;
        outp[(c+0)*NN+n]=(v0-mu)*rs*gam[c+0]+bet[c+0];
        outp[(c+1)*NN+n]=(v1-mu)*rs*gam[c+1]+bet[c+1];
        outp[(c+2)*NN+n]=(v2-mu)*rs*gam[c+2]+bet[c+2];
        outp[(c+3)*NN+n]=(v3-mu)*rs*gam[c+3]+bet[c+3];
        outp[(c+4)*NN+n]=(v4-mu)*rs*gam[c+4]+bet[c+4];
        outp[(c+5)*NN+n]=(v5-mu)*rs*gam[c+5]+bet[c+5];
        outp[(c+6)*NN+n]=(v6-mu)*rs*gam[c+6]+bet[c+6];
        outp[(c+7)*NN+n]=(v7-mu)*rs*gam[c+7]+bet[c+7];
    }
}

// ------------------ Mega GRU v3: weights in LDS (interleaved, conflict-free),
// 2 batches/block, grid 256. Recurrence on wave 0 (both batches, amortized
// weight reads). No register-resident weights -> no allocator fight.
__global__ __launch_bounds__(256,1) void k_grum(
    const float* __restrict__ hlng, const u32* __restrict__ wpk,
    const float* __restrict__ bi1, const float* __restrict__ bh1,
    const float* __restrict__ bi2, const float* __restrict__ bh2,
    const float* __restrict__ Wf, const float* __restrict__ bfv,
    void* __restrict__ outp, const int* __restrict__ flag)
{
    const int b0=blockIdx.x*2, t=threadIdx.x;
    const int wave=t>>6, u=t&63;
    __shared__ __align__(16) u32 s_x[2][1024];     // fp16 x [step][16 u32] : 8 KB
    __shared__ __align__(16) u16 s_xi[2][192*66];  // fp16 xi [row][66 steps-padded] : 50.7 KB
    __shared__ __align__(16) u32 s_y[2][2048];     // fp16 y1 [step][32 u32] : 16 KB
    __shared__ __align__(16) u32 s_w[6144];        // interleaved gate weights : 24 KB
    __shared__ __align__(16) u32 s_h[2][32];
    __shared__ float s_hf[2][64];

    // load x for both batches
    for(int w=t;w<2048;w+=256){
        int bb=w>>10, idx=w&1023;
        const float2* g=(const float2*)(hlng + (size_t)(b0+bb)*2048);
        float2 f=g[idx]; s_x[bb][idx]=packf16(f.x,f.y);
    }
    // load Wh1 interleaved: s_w v4u index = gate*512 + kb*64 + unit
    for(int i=t;i<6144;i+=256){
        int gate=i>>11, rem=i&2047, kb=rem>>8, r2=rem&255, uu=r2>>2, j=r2&3;
        s_w[i] = wpk[6144 + (gate*64+uu)*32 + kb*4 + j];
    }
    __syncthreads();

    // ---- xi1 = x @ Wi1^T + bi1 (384 rows over 256 threads; K=32)
    for(int r=t;r<384;r+=256){
        int bb=r>=192, row=r-bb*192;
        const v4u* wr=(const v4u*)wpk + row*8;
        v4u w0=wr[0],w1=wr[1],w2=wr[2],w3=wr[3];
        float bias=bi1[row];
        u16* o=&s_xi[bb][row*66];
        for(int step=0;step<64;step++){
            const v4u* xp=(const v4u*)&s_x[bb][step*16];
            v4u a0=xp[0],a1=xp[1],a2=xp[2],a3=xp[3];
            float a=bias;
            DOT4(a,a0,w0); DOT4(a,a1,w1); DOT4(a,a2,w2); DOT4(a,a3,w3);
            o[step]=f2h16(a);
        }
    }
    __syncthreads();

    // ---- recurrence 1: wave 0 handles BOTH batches (weights read once per step)
    if(wave==0){
        if(u<32){ s_h[0][u]=0u; s_h[1][u]=0u; }
        const v4u* wv=(const v4u*)s_w;
        float bhr=bh1[u], bhz=bh1[64+u], bhn=bh1[128+u];
        float h0=0.f, h1=0.f;
        const u16* x0r=&s_xi[0][u*66];
        const u16* x0z=&s_xi[0][(64+u)*66];
        const u16* x0n=&s_xi[0][(128+u)*66];
        const u16* x1r=&s_xi[1][u*66];
        const u16* x1z=&s_xi[1][(64+u)*66];
        const u16* x1n=&s_xi[1][(128+u)*66];
        for(int st=0;st<64;st++){
            const v4u* hp0=(const v4u*)s_h[0];
            const v4u* hp1=(const v4u*)s_h[1];
            float gr0=bhr,gz0=bhz,gn0=bhn, gr1=bhr,gz1=bhz,gn1=bhn;
            #pragma unroll
            for(int kb=0;kb<8;kb++){
                v4u wR=wv[kb*64+u], wZ=wv[512+kb*64+u], wN=wv[1024+kb*64+u];
                v4u A=hp0[kb], B=hp1[kb];
                DOT4(gr0,A,wR); DOT4(gz0,A,wZ); DOT4(gn0,A,wN);
                DOT4(gr1,B,wR); DOT4(gz1,B,wZ); DOT4(gn1,B,wN);
            }
            float r0=sigm(h16f(x0r[st])+gr0), z0=sigm(h16f(x0z[st])+gz0);
            float n0=tanh_(h16f(x0n[st]) + r0*gn0);
            h0=(1.f-z0)*n0+z0*h0;
            float r1=sigm(h16f(x1r[st])+gr1), z1=sigm(h16f(x1z[st])+gz1);
            float n1=tanh_(h16f(x1n[st]) + r1*gn1);
            h1=(1.f-z1)*n1+z1*h1;
            u16 hv0=f2h16(h0), hv1=f2h16(h1);
            ((u16*)s_h[0])[u]=hv0; ((u16*)s_h[1])[u]=hv1;   // single-wave lockstep
            ((u16*)s_y[0])[st*64+u]=hv0; ((u16*)s_y[1])[st*64+u]=hv1;
        }
    }
    __syncthreads();

    // ---- reload s_w with Wh2 + compute xi2 = y1 @ Wi2^T + bi2 (K=64)
    for(int i=t;i<6144;i+=256){
        int gate=i>>11, rem=i&2047, kb=rem>>8, r2=rem&255, uu=r2>>2, j=r2&3;
        s_w[i] = wpk[3*6144 + (gate*64+uu)*32 + kb*4 + j];
    }
    for(int r=t;r<384;r+=256){
        int bb=r>=192, row=r-bb*192;
        const v4u* wr=(const v4u*)(wpk + 2*6144) + row*8;
        v4u w0=wr[0],w1=wr[1],w2=wr[2],w3=wr[3],w4=wr[4],w5=wr[5],w6=wr[6],w7=wr[7];
        float bias=bi2[row];
        u16* o=&s_xi[bb][row*66];
        for(int step=0;step<64;step++){
            const v4u* xp=(const v4u*)&s_y[bb][step*32];
            v4u a0=xp[0],a1=xp[1],a2=xp[2],a3=xp[3],a4=xp[4],a5=xp[5],a6=xp[6],a7=xp[7];
            float a=bias;
            DOT32(a,a0,a1,a2,a3,a4,a5,a6,a7,w0,w1,w2,w3,w4,w5,w6,w7);
            o[step]=f2h16(a);
        }
    }
    __syncthreads();

    // ---- recurrence 2: wave 0, both batches
    if(wave==0){
        if(u<32){ s_h[0][u]=0u; s_h[1][u]=0u; }
        const v4u* wv=(const v4u*)s_w;
        float bhr=bh2[u], bhz=bh2[64+u], bhn=bh2[128+u];
        float h0=0.f, h1=0.f;
        const u16* x0r=&s_xi[0][u*66];
        const u16* x0z=&s_xi[0][(64+u)*66];
        const u16* x0n=&s_xi[0][(128+u)*66];
        const u16* x1r=&s_xi[1][u*66];
        const u16* x1z=&s_xi[1][(64+u)*66];
        const u16* x1n=&s_xi[1][(128+u)*66];
        for(int st=0;st<64;st++){
            const v4u* hp0=(const v4u*)s_h[0];
            const v4u* hp1=(const v4u*)s_h[1];
            float gr0=bhr,gz0=bhz,gn0=bhn, gr1=bhr,gz1=bhz,gn1=bhn;
            #pragma unroll
            for(int kb=0;kb<8;kb++){
                v4u wR=wv[kb*64+u], wZ=wv[512+kb*64+u], wN=wv[1024+kb*64+u];
                v4u A=hp0[kb], B=hp1[kb];
                DOT4(gr0,A,wR); DOT4(gz0,A,wZ); DOT4(gn0,A,wN);
                DOT4(gr1,B,wR); DOT4(gz1,B,wZ); DOT4(gn1,B,wN);
            }
            float r0=sigm(h16f(x0r[st])+gr0), z0=sigm(h16f(x0z[st])+gz0);
            float n0=tanh_(h16f(x0n[st]) + r0*gn0);
            h0=(1.f-z0)*n0+z0*h0;
            float r1=sigm(h16f(x1r[st])+gr1), z1=sigm(h16f(x1z[st])+gz1);
            float n1=tanh_(h16f(x1n[st]) + r1*gn1);
            h1=(1.f-z1)*n1+z1*h1;
            ((u16*)s_h[0])[u]=f2h16(h0); ((u16*)s_h[1])[u]=f2h16(h1);
        }
        s_hf[0][u]=h0; s_hf[1][u]=h1;
    }
    __syncthreads();

    // ---- final FC for both batches
    if(t<2*OUT_CH){
        int bb=t/OUT_CH, o=t-bb*OUT_CH;
        float acc=bfv[o];
        const float4* wp=(const float4*)(Wf + o*64);
        const float4* hp=(const float4*)s_hf[bb];
        #pragma unroll
        for(int k=0;k<16;k++){
            float4 w=wp[k], v=hp[k];
            acc += w.x*v.x + w.y*v.y + w.z*v.z + w.w*v.w;
        }
        if(*flag) ((float*)outp)[(b0+bb)*OUT_CH+o]=acc;
        else      ((u16*)outp)[(b0+bb)*OUT_CH+o]=f2bf(acc);
    }
}

extern "C" void kernel_launch(void* const* d_in, const int* in_sizes, int n_in,
                              void* d_out, int out_size, void* d_ws, size_t ws_size,
                              hipStream_t stream)
{
    char* ws=(char*)d_ws;
    int* flag = (int*)ws;
    float* cf = (float*)(ws + 256);
    float* c_x   = cf; cf+=196608;
    float* c_W1  = cf; cf+=6144;
    float* c_as1 = cf; cf+=512;
    float* c_ad1 = cf; cf+=512;
    float* c_b1  = cf; cf+=512;
    float* c_as2 = cf; cf+=64;
    float* c_ad2 = cf; cf+=64;
    float* c_b2  = cf; cf+=64;
    float* c_gam = cf; cf+=64;
    float* c_bet = cf; cf+=64;
    float* c_bi1 = cf; cf+=192;
    float* c_bh1 = cf; cf+=192;
    float* c_bi2 = cf; cf+=192;
    float* c_bh2 = cf; cf+=192;
    float* c_Wf  = cf; cf+=576;
    float* c_bf  = cf; cf+=9;
    uintptr_t p = ((uintptr_t)cf + 255) & ~(uintptr_t)255;
    u16* c_W2i = (u16*)p;                        // 32768 f16 = 64 KB (interleaved)
    p = (p + 32768*2 + 255) & ~(uintptr_t)255;
    u32* wpk = (u32*)p;                          // 4*192*32 u32 = 96 KB (packed GRU weights)
    p = (p + 24576*4 + 255) & ~(uintptr_t)255;
    u32* h1g = (u32*)p;                          // 512*32*256 u32 = 16.78 MB (fp16-packed)
    p = (p + (size_t)BATCH*NN*256*4 + 255) & ~(uintptr_t)255;
    float* hlng = (float*)p;                     // 512*64*32 f32 = 4.19 MB

    const int* ei = (const int*)d_in[1];

    CvtDesc d;
    const int srcIdx[16] = {0,2,3,4,5,7,8,9,10,11,14,15,18,19,20,21};
    void* dsts[16] = {c_x,c_W1,c_as1,c_ad1,c_b1,c_as2,c_ad2,c_b2,c_gam,c_bet,
                      c_bi1,c_bh1,c_bi2,c_bh2,c_Wf,c_bf};
    const int ns[16] = {196608,6144,512,512,512,64,64,64,64,64,
                        192,192,192,192,576,9};
    for(int i=0;i<16;i++){ d.src[i]=d_in[srcIdx[i]]; d.dst[i]=dsts[i]; d.n[i]=ns[i]; }

    k_detect <<<dim3(1),dim3(256),0,stream>>>((const u32*)d_in[0], flag);
    k_convert<<<dim3(16,8),dim3(256),0,stream>>>(d, flag);
    k_prep   <<<dim3(224),dim3(256),0,stream>>>(d_in[6], c_W2i,
                                                d_in[12], d_in[13], d_in[16], d_in[17], wpk, flag);
    k_gat1   <<<dim3(BATCH),dim3(256),0,stream>>>(c_x,ei,c_W1,c_as1,c_ad1,c_b1,h1g);
    k_gat2ln <<<dim3(BATCH),dim3(256),0,stream>>>(h1g,ei,(const uint4*)c_W2i,c_as2,c_ad2,c_b2,c_gam,c_bet,hlng);
    k_grum   <<<dim3(BATCH/2),dim3(256),0,stream>>>(hlng, wpk, c_bi1,c_bh1,c_bi2,c_bh2,
                                                    c_Wf, c_bf, d_out, flag);
}

// Round 14
// 239.539 us; speedup vs baseline: 1.2585x; 1.2585x over previous
//
#include <hip/hip_runtime.h>
#include <hip/hip_bf16.h>
#include <stdint.h>

#define BATCH 512
#define NN 32
#define T_IN 12
#define HID 64
#define HEADS 8
#define OUT_CH 9
#define EPB (NN*8)       // 256 edges per batch (before self loops)
#define ETOT (EPB+NN)    // 288 with self loops
#define F1 (HEADS*HID)   // 512

using u16 = unsigned short;
using u32 = unsigned int;
typedef _Float16 f16;
typedef _Float16 f16x2 __attribute__((ext_vector_type(2)));
typedef u32 v4u __attribute__((ext_vector_type(4)));
typedef float v4f __attribute__((ext_vector_type(4)));

__device__ __forceinline__ float bf2f(u16 u){ return __uint_as_float(((u32)u)<<16); }
__device__ __forceinline__ u16 f2bf(float f){
    u32 x = __float_as_uint(f);
    u32 r = (x + 0x7FFFu + ((x>>16)&1u))>>16;
    return (u16)r;
}
__device__ __forceinline__ u32 packf16(float a, float b){
    f16x2 p; p.x=(f16)a; p.y=(f16)b; return __builtin_bit_cast(u32,p);
}
__device__ __forceinline__ u16 f2h16(float a){ f16 h=(f16)a; return __builtin_bit_cast(u16,h); }
__device__ __forceinline__ float h16f(u16 v){ f16 h=__builtin_bit_cast(f16,v); return (float)h; }
__device__ __forceinline__ float lof(u32 w){ return (float)__builtin_bit_cast(f16x2,w).x; }
__device__ __forceinline__ float hif(u32 w){ return (float)__builtin_bit_cast(f16x2,w).y; }
__device__ __forceinline__ float dot2(u32 a, u32 b, float c){
#if __has_builtin(__builtin_amdgcn_fdot2)
    return __builtin_amdgcn_fdot2(__builtin_bit_cast(f16x2,a), __builtin_bit_cast(f16x2,b), c, false);
#else
    return fmaf(lof(a),lof(b), fmaf(hif(a),hif(b), c));
#endif
}
__device__ __forceinline__ float elu1(float x){ return x > 0.f ? x : (__expf(x)-1.f); }
__device__ __forceinline__ float sigm(float x){ return 1.f/(1.f+__expf(-x)); }
__device__ __forceinline__ float tanh_(float x){ return 1.f - 2.f/(__expf(2.f*x)+1.f); }
__device__ __forceinline__ u32 fenc(float v){
    u32 b=__float_as_uint(v);
    return (b&0x80000000u) ? ~b : (b|0x80000000u);
}
__device__ __forceinline__ float fdec(u32 k){
    return __uint_as_float((k&0x80000000u) ? (k&0x7FFFFFFFu) : ~k);
}

#define DOT4(acc,A,W) do{ acc=dot2(A.x,W.x,acc); acc=dot2(A.y,W.y,acc); \
                          acc=dot2(A.z,W.z,acc); acc=dot2(A.w,W.w,acc); }while(0)

// ------------------------------------------------ canonicalize inputs into ws (fp32)
struct CvtDesc {
    const void* src[16];
    void*       dst[16];
    int         n[16];
};

// merged detect + convert + W2 interleave + GRU weight packing (one launch).
// Every block self-detects dtype from x (deterministic); block 0 publishes flag.
__global__ __launch_bounds__(256) void k_setup(
    const u32* __restrict__ xw, CvtDesc d,
    const void* __restrict__ W2src, u16* __restrict__ W2i,
    const void* __restrict__ Wi1, const void* __restrict__ Wh1,
    const void* __restrict__ Wi2, const void* __restrict__ Wh2,
    u32* __restrict__ wpk, int* __restrict__ flag)
{
    __shared__ int cnt;
    if(threadIdx.x==0) cnt=0;
    __syncthreads();
    int c=0;
    for(int i=threadIdx.x;i<4096;i+=256){
        u32 w=xw[i];
        if(w & 0x7FFFFFFFu){
            u32 el=(w>>7)&0xFFu;
            if(el>=0x90u) c++;
        }
    }
    atomicAdd(&cnt,c);
    __syncthreads();
    const int f = (cnt>256) ? 1 : 0;   // 1 = fp32 inputs, 0 = bf16
    if(blockIdx.x==0 && threadIdx.x==0) *flag=f;

    const int bk=blockIdx.x;
    if(bk<128){
        // convert: 16 segments x 8 sub-blocks
        int seg=bk>>3, sub=bk&7;
        const void* s=d.src[seg];
        float* o=(float*)d.dst[seg];
        int n=d.n[seg];
        for(int i=sub*256+threadIdx.x;i<n;i+=2048)
            o[i] = f ? ((const float*)s)[i] : bf2f(((const u16*)s)[i]);
    } else if(bk<256){
        // W2 [512][64] -> interleaved fp16 W2i[(k>>3)*64+j][k&7]
        int i=(bk-128)*256+threadIdx.x;
        int k=i>>6, j=i&63;
        float v = f? ((const float*)W2src)[i] : bf2f(((const u16*)W2src)[i]);
        W2i[ (((size_t)(k>>3)*64 + j)<<3) + (k&7) ] = f2h16(v);
    } else {
        // GRU weights -> packed fp16 [4][192 rows][32 u32] (K=64, Wi1 zero-padded)
        int w=(bk-256)*256+threadIdx.x;
        int m=w/6144;
        int rem=w-m*6144;
        int row=rem>>5, kw=rem&31;
        const void* s=(m==0)?Wi1:(m==1)?Wh1:(m==2)?Wi2:Wh2;
        int K=(m==0)?32:64;
        int k0=2*kw, k1=k0+1;
        float v0=0.f, v1=0.f;
        if(k0<K) v0 = f? ((const float*)s)[row*K+k0] : bf2f(((const u16*)s)[row*K+k0]);
        if(k1<K) v1 = f? ((const float*)s)[row*K+k1] : bf2f(((const u16*)s)[row*K+k1]);
        wpk[w]=packf16(v0,v1);
    }
}

// ---------------------------------------------------------------- GAT layer 1
__global__ __launch_bounds__(256,2) void k_gat1(
    const float* __restrict__ x, const int* __restrict__ ei,
    const float* __restrict__ W1, const float* __restrict__ a_s, const float* __restrict__ a_d,
    const float* __restrict__ b1, u32* __restrict__ h1g)
{
    const int b = blockIdx.x, t = threadIdx.x;
    __shared__ __align__(16) float s_x[NN][12];
    __shared__ float s_W1[T_IN*F1];
    __shared__ __align__(16) u16 s_h[NN][520];
    __shared__ __align__(16) u32 s_aspk[HEADS*32], s_adpk[HEADS*32];
    __shared__ float s_es[NN][HEADS], s_ed[NN][HEADS];
    __shared__ unsigned char s_src[ETOT], s_dst[ETOT];
    __shared__ float s_al[HEADS][ETOT];
    __shared__ u32 s_mx[NN*HEADS];
    __shared__ float s_sm[NN*HEADS], s_inv[NN*HEADS];
    __shared__ int s_cnt[NN], s_off[NN], s_fil[NN];
    __shared__ short s_lst[ETOT];

    for(int i=t;i<NN*T_IN;i+=256) s_x[i/12][i%12] = x[b*NN*T_IN + i];
    for(int i=t;i<T_IN*F1;i+=256) s_W1[i]=W1[i];
    s_aspk[t]=packf16(a_s[2*t],a_s[2*t+1]);
    s_adpk[t]=packf16(a_d[2*t],a_d[2*t+1]);
    s_mx[t]=0u; s_sm[t]=0.f;
    if(t<EPB){
        s_src[t] = (unsigned char)(ei[b*EPB+t] - b*NN);
        s_dst[t] = (unsigned char)(ei[(size_t)BATCH*EPB + b*EPB+t] - b*NN);
    }
    if(t<NN){ s_src[EPB+t]=s_dst[EPB+t]=(unsigned char)t; s_cnt[t]=0; s_fil[t]=0; }
    __syncthreads();

    {
        v4f Wa0,Wa1,Wa2,Wb0,Wb1,Wb2;
        Wa0.x=s_W1[0*F1+t]; Wa0.y=s_W1[1*F1+t]; Wa0.z=s_W1[2*F1+t]; Wa0.w=s_W1[3*F1+t];
        Wa1.x=s_W1[4*F1+t]; Wa1.y=s_W1[5*F1+t]; Wa1.z=s_W1[6*F1+t]; Wa1.w=s_W1[7*F1+t];
        Wa2.x=s_W1[8*F1+t]; Wa2.y=s_W1[9*F1+t]; Wa2.z=s_W1[10*F1+t]; Wa2.w=s_W1[11*F1+t];
        Wb0.x=s_W1[0*F1+t+256]; Wb0.y=s_W1[1*F1+t+256]; Wb0.z=s_W1[2*F1+t+256]; Wb0.w=s_W1[3*F1+t+256];
        Wb1.x=s_W1[4*F1+t+256]; Wb1.y=s_W1[5*F1+t+256]; Wb1.z=s_W1[6*F1+t+256]; Wb1.w=s_W1[7*F1+t+256];
        Wb2.x=s_W1[8*F1+t+256]; Wb2.y=s_W1[9*F1+t+256]; Wb2.z=s_W1[10*F1+t+256]; Wb2.w=s_W1[11*F1+t+256];
        for(int n=0;n<NN;n++){
            const float4* xp=(const float4*)s_x[n];
            float4 xa=xp[0], xb=xp[1], xc=xp[2];
            float A=0.f,B=0.f;
            A=fmaf(xa.x,Wa0.x,A); A=fmaf(xa.y,Wa0.y,A); A=fmaf(xa.z,Wa0.z,A); A=fmaf(xa.w,Wa0.w,A);
            A=fmaf(xb.x,Wa1.x,A); A=fmaf(xb.y,Wa1.y,A); A=fmaf(xb.z,Wa1.z,A); A=fmaf(xb.w,Wa1.w,A);
            A=fmaf(xc.x,Wa2.x,A); A=fmaf(xc.y,Wa2.y,A); A=fmaf(xc.z,Wa2.z,A); A=fmaf(xc.w,Wa2.w,A);
            B=fmaf(xa.x,Wb0.x,B); B=fmaf(xa.y,Wb0.y,B); B=fmaf(xa.z,Wb0.z,B); B=fmaf(xa.w,Wb0.w,B);
            B=fmaf(xb.x,Wb1.x,B); B=fmaf(xb.y,Wb1.y,B); B=fmaf(xb.z,Wb1.z,B); B=fmaf(xb.w,Wb1.w,B);
            B=fmaf(xc.x,Wb2.x,B); B=fmaf(xc.y,Wb2.y,B); B=fmaf(xc.z,Wb2.z,B); B=fmaf(xc.w,Wb2.w,B);
            s_h[n][t]=f2h16(A); s_h[n][t+256]=f2h16(B);
        }
    }
    for(int e=t;e<ETOT;e+=256) atomicAdd(&s_cnt[s_dst[e]],1);
    __syncthreads();

    {
        int n=t&31, hd=t>>5;
        const v4u* hp=(const v4u*)((const u16*)s_h[n] + hd*64);
        v4u h0=hp[0],h1=hp[1],h2=hp[2],h3=hp[3],h4=hp[4],h5=hp[5],h6=hp[6],h7=hp[7];
        const v4u* ap=(const v4u*)&s_aspk[hd*32];
        const v4u* dp=(const v4u*)&s_adpk[hd*32];
        float e1=0.f,e2=0.f;
        { v4u w=ap[0]; DOT4(e1,h0,w); w=ap[1]; DOT4(e1,h1,w); w=ap[2]; DOT4(e1,h2,w); w=ap[3]; DOT4(e1,h3,w);
          w=ap[4]; DOT4(e1,h4,w); w=ap[5]; DOT4(e1,h5,w); w=ap[6]; DOT4(e1,h6,w); w=ap[7]; DOT4(e1,h7,w); }
        { v4u w=dp[0]; DOT4(e2,h0,w); w=dp[1]; DOT4(e2,h1,w); w=dp[2]; DOT4(e2,h2,w); w=dp[3]; DOT4(e2,h3,w);
          w=dp[4]; DOT4(e2,h4,w); w=dp[5]; DOT4(e2,h5,w); w=dp[6]; DOT4(e2,h6,w); w=dp[7]; DOT4(e2,h7,w); }
        s_es[n][hd]=e1; s_ed[n][hd]=e2;
    }
    if(t==0){ int o=0; for(int i=0;i<NN;i++){ s_off[i]=o; o+=s_cnt[i]; } }
    __syncthreads();

    for(int e=t;e<ETOT;e+=256){
        int d=s_dst[e]; int p=atomicAdd(&s_fil[d],1); s_lst[s_off[d]+p]=(short)e;
    }
    for(int i=t;i<ETOT*HEADS;i+=256){
        int hd=i/ETOT, e=i-hd*ETOT;
        int sr=s_src[e], d=s_dst[e];
        float v = s_es[sr][hd]+s_ed[d][hd];
        v = v>0.f? v : 0.2f*v;
        s_al[hd][e]=v;
        atomicMax(&s_mx[d*8+hd], fenc(v));
    }
    __syncthreads();

    for(int i=t;i<ETOT*HEADS;i+=256){
        int hd=i/ETOT, e=i-hd*ETOT;
        int d=s_dst[e];
        float p=__expf(s_al[hd][e]-fdec(s_mx[d*8+hd]));
        s_al[hd][e]=p;
        atomicAdd(&s_sm[d*8+hd], p);
    }
    __syncthreads();
    s_inv[t]=1.f/(s_sm[t]+1e-16f);
    __syncthreads();

    {
        int d=t&31, hd=t>>5;
        int o=s_off[d], cnt=s_cnt[d];
        float inv=s_inv[d*8+hd];
        size_t obase = ((size_t)(b*NN+d))*256 + hd*32;
        #pragma unroll
        for(int ch=0;ch<2;ch++){
            v4f a0=0,a1=0,a2=0,a3=0,a4=0,a5=0,a6=0,a7=0;
            for(int i=0;i<cnt;i++){
                int e=s_lst[o+i]; float av=s_al[hd][e]; int sr=s_src[e];
                const v4u* hp=(const v4u*)((const u16*)s_h[sr] + hd*64 + ch*32);
                v4u p0=hp[0],p1=hp[1],p2=hp[2],p3=hp[3];
                a0.x=fmaf(av,lof(p0.x),a0.x); a0.y=fmaf(av,hif(p0.x),a0.y);
                a0.z=fmaf(av,lof(p0.y),a0.z); a0.w=fmaf(av,hif(p0.y),a0.w);
                a1.x=fmaf(av,lof(p0.z),a1.x); a1.y=fmaf(av,hif(p0.z),a1.y);
                a1.z=fmaf(av,lof(p0.w),a1.z); a1.w=fmaf(av,hif(p0.w),a1.w);
                a2.x=fmaf(av,lof(p1.x),a2.x); a2.y=fmaf(av,hif(p1.x),a2.y);
                a2.z=fmaf(av,lof(p1.y),a2.z); a2.w=fmaf(av,hif(p1.y),a2.w);
                a3.x=fmaf(av,lof(p1.z),a3.x); a3.y=fmaf(av,hif(p1.z),a3.y);
                a3.z=fmaf(av,lof(p1.w),a3.z); a3.w=fmaf(av,hif(p1.w),a3.w);
                a4.x=fmaf(av,lof(p2.x),a4.x); a4.y=fmaf(av,hif(p2.x),a4.y);
                a4.z=fmaf(av,lof(p2.y),a4.z); a4.w=fmaf(av,hif(p2.y),a4.w);
                a5.x=fmaf(av,lof(p2.z),a5.x); a5.y=fmaf(av,hif(p2.z),a5.y);
                a5.z=fmaf(av,lof(p2.w),a5.z); a5.w=fmaf(av,hif(p2.w),a5.w);
                a6.x=fmaf(av,lof(p3.x),a6.x); a6.y=fmaf(av,hif(p3.x),a6.y);
                a6.z=fmaf(av,lof(p3.y),a6.z); a6.w=fmaf(av,hif(p3.y),a6.w);
                a7.x=fmaf(av,lof(p3.z),a7.x); a7.y=fmaf(av,hif(p3.z),a7.y);
                a7.z=fmaf(av,lof(p3.w),a7.z); a7.w=fmaf(av,hif(p3.w),a7.w);
            }
            const float* bp = b1 + hd*64 + ch*32;
            u32* op = h1g + obase + ch*16;
            op[0] = packf16(elu1(a0.x*inv+bp[0]),  elu1(a0.y*inv+bp[1]));
            op[1] = packf16(elu1(a0.z*inv+bp[2]),  elu1(a0.w*inv+bp[3]));
            op[2] = packf16(elu1(a1.x*inv+bp[4]),  elu1(a1.y*inv+bp[5]));
            op[3] = packf16(elu1(a1.z*inv+bp[6]),  elu1(a1.w*inv+bp[7]));
            op[4] = packf16(elu1(a2.x*inv+bp[8]),  elu1(a2.y*inv+bp[9]));
            op[5] = packf16(elu1(a2.z*inv+bp[10]), elu1(a2.w*inv+bp[11]));
            op[6] = packf16(elu1(a3.x*inv+bp[12]), elu1(a3.y*inv+bp[13]));
            op[7] = packf16(elu1(a3.z*inv+bp[14]), elu1(a3.w*inv+bp[15]));
            op[8] = packf16(elu1(a4.x*inv+bp[16]), elu1(a4.y*inv+bp[17]));
            op[9] = packf16(elu1(a4.z*inv+bp[18]), elu1(a4.w*inv+bp[19]));
            op[10]= packf16(elu1(a5.x*inv+bp[20]), elu1(a5.y*inv+bp[21]));
            op[11]= packf16(elu1(a5.z*inv+bp[22]), elu1(a5.w*inv+bp[23]));
            op[12]= packf16(elu1(a6.x*inv+bp[24]), elu1(a6.y*inv+bp[25]));
            op[13]= packf16(elu1(a6.z*inv+bp[26]), elu1(a6.w*inv+bp[27]));
            op[14]= packf16(elu1(a7.x*inv+bp[28]), elu1(a7.y*inv+bp[29]));
            op[15]= packf16(elu1(a7.z*inv+bp[30]), elu1(a7.w*inv+bp[31]));
        }
    }
}

// --------------------------------------------- GAT layer 2 + LayerNorm (+transpose)
__global__ __launch_bounds__(256,2) void k_gat2ln(
    const u32* __restrict__ h1g, const int* __restrict__ ei,
    const uint4* __restrict__ W2i, const float* __restrict__ a_s2, const float* __restrict__ a_d2,
    const float* __restrict__ b2, const float* __restrict__ gam, const float* __restrict__ bet,
    float* __restrict__ hlng)
{
    const int b=blockIdx.x, t=threadIdx.x;
    __shared__ __align__(16) u32 s_h1[NN*260];
    __shared__ float s_h2[NN][HID];
    __shared__ float s_es[NN], s_ed[NN];
    __shared__ unsigned char s_src[ETOT], s_dst[ETOT];
    __shared__ float s_al[ETOT];
    __shared__ u32 s_mx[NN];
    __shared__ float s_sm[NN], s_inv[NN];
    __shared__ int s_cnt[NN], s_off[NN], s_fil[NN];
    __shared__ short s_lst[ETOT];

    { const u32* g = h1g + (size_t)b*8192;
      for(int w=t; w<8192; w+=256){ int n=w>>8, c=w&255; s_h1[n*260+c]=g[w]; } }
    if(t<EPB){
        s_src[t]=(unsigned char)(ei[b*EPB+t]-b*NN);
        s_dst[t]=(unsigned char)(ei[(size_t)BATCH*EPB+b*EPB+t]-b*NN);
    }
    if(t<NN){ s_src[EPB+t]=s_dst[EPB+t]=(unsigned char)t;
              s_cnt[t]=0; s_fil[t]=0; s_mx[t]=0u; s_sm[t]=0.f; }
    __syncthreads();

    for(int e=t;e<ETOT;e+=256) atomicAdd(&s_cnt[s_dst[e]],1);
    {
        int n0=(t>>5)<<2, j0=(t&31)<<1;
        const u32* r0=&s_h1[(n0+0)*260];
        const u32* r1=&s_h1[(n0+1)*260];
        const u32* r2=&s_h1[(n0+2)*260];
        const u32* r3=&s_h1[(n0+3)*260];
        float a00=0,a01=0,a10=0,a11=0,a20=0,a21=0,a30=0,a31=0;
        for(int kb=0;kb<64;kb++){
            uint4 A0=*(const uint4*)&r0[kb*4];
            uint4 A1=*(const uint4*)&r1[kb*4];
            uint4 A2=*(const uint4*)&r2[kb*4];
            uint4 A3=*(const uint4*)&r3[kb*4];
            const uint4* wp=&W2i[kb*64+j0];
            uint4 w0=wp[0], w1=wp[1];
            a00=dot2(A0.x,w0.x,a00); a00=dot2(A0.y,w0.y,a00); a00=dot2(A0.z,w0.z,a00); a00=dot2(A0.w,w0.w,a00);
            a01=dot2(A0.x,w1.x,a01); a01=dot2(A0.y,w1.y,a01); a01=dot2(A0.z,w1.z,a01); a01=dot2(A0.w,w1.w,a01);
            a10=dot2(A1.x,w0.x,a10); a10=dot2(A1.y,w0.y,a10); a10=dot2(A1.z,w0.z,a10); a10=dot2(A1.w,w0.w,a10);
            a11=dot2(A1.x,w1.x,a11); a11=dot2(A1.y,w1.y,a11); a11=dot2(A1.z,w1.z,a11); a11=dot2(A1.w,w1.w,a11);
            a20=dot2(A2.x,w0.x,a20); a20=dot2(A2.y,w0.y,a20); a20=dot2(A2.z,w0.z,a20); a20=dot2(A2.w,w0.w,a20);
            a21=dot2(A2.x,w1.x,a21); a21=dot2(A2.y,w1.y,a21); a21=dot2(A2.z,w1.z,a21); a21=dot2(A2.w,w1.w,a21);
            a30=dot2(A3.x,w0.x,a30); a30=dot2(A3.y,w0.y,a30); a30=dot2(A3.z,w0.z,a30); a30=dot2(A3.w,w0.w,a30);
            a31=dot2(A3.x,w1.x,a31); a31=dot2(A3.y,w1.y,a31); a31=dot2(A3.z,w1.z,a31); a31=dot2(A3.w,w1.w,a31);
        }
        s_h2[n0+0][j0]=a00; s_h2[n0+0][j0+1]=a01;
        s_h2[n0+1][j0]=a10; s_h2[n0+1][j0+1]=a11;
        s_h2[n0+2][j0]=a20; s_h2[n0+2][j0+1]=a21;
        s_h2[n0+3][j0]=a30; s_h2[n0+3][j0+1]=a31;
    }
    __syncthreads();

    {
        int n=t>>3, g=t&7;
        float e1=0,e2=0;
        #pragma unroll
        for(int cc=0; cc<8; cc++){
            float hv = s_h2[n][g*8+cc];
            e1 += hv*a_s2[g*8+cc];
            e2 += hv*a_d2[g*8+cc];
        }
        #pragma unroll
        for(int m=1;m<8;m<<=1){ e1 += __shfl_xor(e1,m,64); e2 += __shfl_xor(e2,m,64); }
        if(g==0){ s_es[n]=e1; s_ed[n]=e2; }
    }
    if(t==0){ int o=0; for(int i=0;i<NN;i++){ s_off[i]=o; o+=s_cnt[i]; } }
    __syncthreads();

    for(int e=t;e<ETOT;e+=256){
        int d=s_dst[e]; int p=atomicAdd(&s_fil[d],1); s_lst[s_off[d]+p]=(short)e;
    }
    for(int e=t;e<ETOT;e+=256){
        int d=s_dst[e];
        float v = s_es[s_src[e]] + s_ed[d];
        v = v>0.f? v:0.2f*v;
        s_al[e]=v;
        atomicMax(&s_mx[d], fenc(v));
    }
    __syncthreads();

    for(int e=t;e<ETOT;e+=256){
        int d=s_dst[e];
        float p=__expf(s_al[e]-fdec(s_mx[d]));
        s_al[e]=p;
        atomicAdd(&s_sm[d], p);
    }
    __syncthreads();
    if(t<NN) s_inv[t]=1.f/(s_sm[t]+1e-16f);
    __syncthreads();

    {
        int n=t>>3, g=t&7;
        v4f a0=0, a1=0;
        int o=s_off[n], cnt=s_cnt[n];
        float inv=s_inv[n];
        for(int i=0;i<cnt;i++){
            int e=s_lst[o+i]; float a=s_al[e]; int sr=s_src[e];
            const float4* hp=(const float4*)&s_h2[sr][g*8];
            float4 v0=hp[0], v1=hp[1];
            a0.x=fmaf(a,v0.x,a0.x); a0.y=fmaf(a,v0.y,a0.y); a0.z=fmaf(a,v0.z,a0.z); a0.w=fmaf(a,v0.w,a0.w);
            a1.x=fmaf(a,v1.x,a1.x); a1.y=fmaf(a,v1.y,a1.y); a1.z=fmaf(a,v1.z,a1.z); a1.w=fmaf(a,v1.w,a1.w);
        }
        const float* bp=b2+g*8;
        float v0=elu1(a0.x*inv+bp[0]), v1=elu1(a0.y*inv+bp[1]);
        float v2=elu1(a0.z*inv+bp[2]), v3=elu1(a0.w*inv+bp[3]);
        float v4=elu1(a1.x*inv+bp[4]), v5=elu1(a1.y*inv+bp[5]);
        float v6=elu1(a1.z*inv+bp[6]), v7=elu1(a1.w*inv+bp[7]);
        float sum=v0+v1+v2+v3+v4+v5+v6+v7;
        float sq=v0*v0+v1*v1+v2*v2+v3*v3+v4*v4+v5*v5+v6*v6+v7*v7;
        #pragma unroll
        for(int m=1;m<8;m<<=1){ sum+=__shfl_xor(sum,m,64); sq+=__shfl_xor(sq,m,64); }
        float mu = sum*(1.f/64.f);
        float var = sq*(1.f/64.f) - mu*mu;
        float rs = rsqrtf(var + 1e-5f);
        float* outp = hlng + (size_t)b*HID*NN;
        int c=g*8;
        outp[(c+0)*NN+n]=(v0-mu)*rs*gam[c+0]+bet[c+0];
        outp[(c+1)*NN+n]=(v1-mu)*rs*gam[c+1]+bet[c+1];
        outp[(c+2)*NN+n]=(v2-mu)*rs*gam[c+2]+bet[c+2];
        outp[(c+3)*NN+n]=(v3-mu)*rs*gam[c+3]+bet[c+3];
        outp[(c+4)*NN+n]=(v4-mu)*rs*gam[c+4]+bet[c+4];
        outp[(c+5)*NN+n]=(v5-mu)*rs*gam[c+5]+bet[c+5];
        outp[(c+6)*NN+n]=(v6-mu)*rs*gam[c+6]+bet[c+6];
        outp[(c+7)*NN+n]=(v7-mu)*rs*gam[c+7]+bet[c+7];
    }
}

// --------------------------------- Fused GRU (r6 structure, proven 65.5us),
// weights element-loaded from prepacked fp16 wpk (half the reload bytes of r6).
// 256 threads = 4 waves. waves 0-1: GRU1 (units 0-31 / 32-63); waves 2-3: GRU2.
// Within a wave: lane = uu + 32*s (s = k-half). Partials combine via shfl_xor(32).
__global__ __launch_bounds__(256,2) void k_gruf(
    const float* __restrict__ hlng, const u32* __restrict__ wpk,
    const float* __restrict__ bi1, const float* __restrict__ bh1,
    const float* __restrict__ bi2, const float* __restrict__ bh2,
    const float* __restrict__ Wf, const float* __restrict__ bfv,
    void* __restrict__ outp, const int* __restrict__ flag)
{
    const int b=blockIdx.x, t=threadIdx.x;
    const int wave=t>>6, lane=t&63;
    const int layer=wave>>1;        // 0 = GRU1, 1 = GRU2
    const int ublk=wave&1;          // unit block
    const int uu=lane&31, s=lane>>5;
    const int u=ublk*32+uu;         // hidden unit

    __shared__ __align__(16) u32 s_x1[64*16];   // GRU1 input fp16-packed [step][16]
    __shared__ __align__(16) u32 s_h1[2][32];   // h1/y1 double buffer (64 f16)
    __shared__ __align__(16) u32 s_h2[2][32];   // h2 double buffer
    __shared__ float s_h2f[64];

    { const float2* g=(const float2*)(hlng + (size_t)b*2048);
      for(int w=t;w<1024;w+=256){ float2 v=g[w]; s_x1[w]=packf16(v.x,v.y); } }
    if(t<32){ s_h1[0][t]=0u; s_h1[1][t]=0u; s_h2[0][t]=0u; s_h2[1][t]=0u; }

    // per-lane packed half-row weights (element u32 loads from wpk, r6 pattern)
    u32 wiR[16],wiZ[16],wiN[16],whR[16],whZ[16],whN[16];
    const u32* wiu = wpk + (size_t)(layer*2+0)*6144;
    const u32* whu = wpk + (size_t)(layer*2+1)*6144;
    if(layer==0){
        #pragma unroll
        for(int k=0;k<8;k++){
            wiR[k]=wiu[u*32+s*8+k];
            wiZ[k]=wiu[(64+u)*32+s*8+k];
            wiN[k]=wiu[(128+u)*32+s*8+k];
        }
        #pragma unroll
        for(int k=0;k<16;k++){
            whR[k]=whu[u*32+s*16+k];
            whZ[k]=whu[(64+u)*32+s*16+k];
            whN[k]=whu[(128+u)*32+s*16+k];
        }
    } else {
        #pragma unroll
        for(int k=0;k<16;k++){
            wiR[k]=wiu[u*32+s*16+k];
            wiZ[k]=wiu[(64+u)*32+s*16+k];
            wiN[k]=wiu[(128+u)*32+s*16+k];
            whR[k]=whu[u*32+s*16+k];
            whZ[k]=whu[(64+u)*32+s*16+k];
            whN[k]=whu[(128+u)*32+s*16+k];
        }
    }
    const float* bi = layer? bi2:bi1;
    const float* bh = layer? bh2:bh1;
    float br=bi[u]+bh[u], bz=bi[64+u]+bh[64+u], bxn=bi[128+u], bhn=bh[128+u];
    float h=0.f;
    __syncthreads();

    for(int it=0; it<=64; ++it){
        const int pb=(it-1)&1, cb=it&1;
        bool act;
        float pr=0.f,pz=0.f,pxn=0.f,phn=0.f;
        if(layer==0){
            act=(it<64);
            if(act){
                const u32* xp=&s_x1[it*16+s*8];
                const u32* hp=&s_h1[pb][s*16];
                #pragma unroll
                for(int k=0;k<8;k++){ u32 xv=xp[k]; pr=dot2(xv,wiR[k],pr); pz=dot2(xv,wiZ[k],pz); pxn=dot2(xv,wiN[k],pxn); }
                #pragma unroll
                for(int k=0;k<16;k++){ u32 hv=hp[k]; pr=dot2(hv,whR[k],pr); pz=dot2(hv,whZ[k],pz); phn=dot2(hv,whN[k],phn); }
            }
        } else {
            act=(it>=1);
            if(act){
                const u32* xp=&s_h1[pb][s*16];   // y1[it-1]
                const u32* hp=&s_h2[pb][s*16];
                #pragma unroll
                for(int k=0;k<16;k++){
                    u32 xv=xp[k], hv=hp[k];
                    pr=dot2(xv,wiR[k],pr); pz=dot2(xv,wiZ[k],pz); pxn=dot2(xv,wiN[k],pxn);
                    pr=dot2(hv,whR[k],pr); pz=dot2(hv,whZ[k],pz); phn=dot2(hv,whN[k],phn);
                }
            }
        }
        if(act){
            pr  += __shfl_xor(pr ,32,64);
            pz  += __shfl_xor(pz ,32,64);
            pxn += __shfl_xor(pxn,32,64);
            phn += __shfl_xor(phn,32,64);
            float r=sigm(pr+br), z=sigm(pz+bz);
            float n=tanh_(pxn+bxn + r*(phn+bhn));
            h=(1.f-z)*n + z*h;
            if(s==0){
                u16 hv=f2h16(h);
                if(layer==0) ((u16*)s_h1[cb])[u]=hv;
                else { ((u16*)s_h2[cb])[u]=hv; if(it==64) s_h2f[u]=h; }
            }
        }
        __syncthreads();
    }

    if(t<OUT_CH){
        float acc=bfv[t];
        const float4* wp=(const float4*)(Wf + t*64);
        const float4* hp=(const float4*)s_h2f;
        #pragma unroll
        for(int k=0;k<16;k++){
            float4 w=wp[k], v=hp[k];
            acc += w.x*v.x + w.y*v.y + w.z*v.z + w.w*v.w;
        }
        if(*flag) ((float*)outp)[b*OUT_CH+t]=acc;
        else      ((u16*)outp)[b*OUT_CH+t]=f2bf(acc);
    }
}

extern "C" void kernel_launch(void* const* d_in, const int* in_sizes, int n_in,
                              void* d_out, int out_size, void* d_ws, size_t ws_size,
                              hipStream_t stream)
{
    char* ws=(char*)d_ws;
    int* flag = (int*)ws;
    float* cf = (float*)(ws + 256);
    float* c_x   = cf; cf+=196608;
    float* c_W1  = cf; cf+=6144;
    float* c_as1 = cf; cf+=512;
    float* c_ad1 = cf; cf+=512;
    float* c_b1  = cf; cf+=512;
    float* c_as2 = cf; cf+=64;
    float* c_ad2 = cf; cf+=64;
    float* c_b2  = cf; cf+=64;
    float* c_gam = cf; cf+=64;
    float* c_bet = cf; cf+=64;
    float* c_bi1 = cf; cf+=192;
    float* c_bh1 = cf; cf+=192;
    float* c_bi2 = cf; cf+=192;
    float* c_bh2 = cf; cf+=192;
    float* c_Wf  = cf; cf+=576;
    float* c_bf  = cf; cf+=9;
    uintptr_t p = ((uintptr_t)cf + 255) & ~(uintptr_t)255;
    u16* c_W2i = (u16*)p;                        // 32768 f16 = 64 KB (interleaved)
    p = (p + 32768*2 + 255) & ~(uintptr_t)255;
    u32* wpk = (u32*)p;                          // 4*192*32 u32 = 96 KB (packed GRU weights)
    p = (p + 24576*4 + 255) & ~(uintptr_t)255;
    u32* h1g = (u32*)p;                          // 512*32*256 u32 = 16.78 MB (fp16-packed)
    p = (p + (size_t)BATCH*NN*256*4 + 255) & ~(uintptr_t)255;
    float* hlng = (float*)p;                     // 512*64*32 f32 = 4.19 MB

    const int* ei = (const int*)d_in[1];

    CvtDesc d;
    const int srcIdx[16] = {0,2,3,4,5,7,8,9,10,11,14,15,18,19,20,21};
    void* dsts[16] = {c_x,c_W1,c_as1,c_ad1,c_b1,c_as2,c_ad2,c_b2,c_gam,c_bet,
                      c_bi1,c_bh1,c_bi2,c_bh2,c_Wf,c_bf};
    const int ns[16] = {196608,6144,512,512,512,64,64,64,64,64,
                        192,192,192,192,576,9};
    for(int i=0;i<16;i++){ d.src[i]=d_in[srcIdx[i]]; d.dst[i]=dsts[i]; d.n[i]=ns[i]; }

    k_setup  <<<dim3(352),dim3(256),0,stream>>>((const u32*)d_in[0], d,
                                                d_in[6], c_W2i,
                                                d_in[12], d_in[13], d_in[16], d_in[17],
                                                wpk, flag);
    k_gat1   <<<dim3(BATCH),dim3(256),0,stream>>>(c_x,ei,c_W1,c_as1,c_ad1,c_b1,h1g);
    k_gat2ln <<<dim3(BATCH),dim3(256),0,stream>>>(h1g,ei,(const uint4*)c_W2i,c_as2,c_ad2,c_b2,c_gam,c_bet,hlng);
    k_gruf   <<<dim3(BATCH),dim3(256),0,stream>>>(hlng, wpk, c_bi1,c_bh1,c_bi2,c_bh2,
                                                  c_Wf, c_bf, d_out, flag);
}